// Round 15
// baseline (442.832 us; speedup 1.0000x reference)
//
#include <hip/hip_runtime.h>
#include <math.h>

#define S_ 1024
#define D_ 256

typedef __attribute__((ext_vector_type(8))) _Float16 half8;
typedef __attribute__((ext_vector_type(4))) _Float16 half4;
typedef __attribute__((ext_vector_type(2))) _Float16 half2v;
typedef __attribute__((ext_vector_type(4))) float f32x4;
typedef __attribute__((ext_vector_type(4))) unsigned int u32x4;

__device__ __forceinline__ float wave_sum64(float x) {
    x += __shfl_xor(x, 32); x += __shfl_xor(x, 16); x += __shfl_xor(x, 8);
    x += __shfl_xor(x, 4);  x += __shfl_xor(x, 2);  x += __shfl_xor(x, 1);
    return x;
}

#define GLD16(gp, lp) __builtin_amdgcn_global_load_lds( \
    (const __attribute__((address_space(1))) void*)(gp), \
    (__attribute__((address_space(3))) void*)(lp), 16, 0, 0)

// ---------------- weight prep: transpose + fp16 convert ----------------
__global__ __launch_bounds__(256) void transpose_cvt(
    const float* __restrict__ src, _Float16* __restrict__ dst, int K, int N)
{
    __shared__ float tile[32][33];
    src += (size_t)blockIdx.z * K * N;
    dst += (size_t)blockIdx.z * K * N;
    const int bx = blockIdx.x * 32;   // n
    const int by = blockIdx.y * 32;   // k
    const int t = threadIdx.x;
    const int c = t & 31, r0 = t >> 5;
    #pragma unroll
    for (int j = 0; j < 4; ++j)
        tile[r0 + 8 * j][c] = src[(size_t)(by + r0 + 8 * j) * N + bx + c];
    __syncthreads();
    #pragma unroll
    for (int j = 0; j < 4; ++j)
        dst[(size_t)(bx + r0 + 8 * j) * K + by + c] = (_Float16)tile[c][r0 + 8 * j];
}

__global__ __launch_bounds__(256) void transpose_qkv(
    const float* __restrict__ Wq, const float* __restrict__ Wk,
    const float* __restrict__ Wv, _Float16* __restrict__ qkvT)
{
    __shared__ float tile[32][33];
    const int z = blockIdx.z, l = z / 3, m = z % 3;
    const float* src = (m == 0 ? Wq : (m == 1 ? Wk : Wv)) + (size_t)l * 65536;
    _Float16* dst = qkvT + (size_t)l * 196608 + (size_t)m * 65536;
    const int bx = blockIdx.x * 32;
    const int by = blockIdx.y * 32;
    const int t = threadIdx.x;
    const int c = t & 31, r0 = t >> 5;
    #pragma unroll
    for (int j = 0; j < 4; ++j)
        tile[r0 + 8 * j][c] = src[(size_t)(by + r0 + 8 * j) * 256 + bx + c];
    __syncthreads();
    #pragma unroll
    for (int j = 0; j < 4; ++j)
        dst[(size_t)(bx + r0 + 8 * j) * 256 + by + c] = (_Float16)tile[c][r0 + 8 * j];
}

__global__ __launch_bounds__(256) void pack_bias(
    const float* __restrict__ bq, const float* __restrict__ bk,
    const float* __restrict__ bv, float* __restrict__ bqkv)
{
    const int z = blockIdx.x, l = z / 3, m = z % 3;
    const float* s = (m == 0 ? bq : (m == 1 ? bk : bv)) + l * 256;
    bqkv[l * 768 + m * 256 + threadIdx.x] = s[threadIdx.x];
}

// ---------------- embed + LN (4 tokens per 256-thr block) ----------------
__global__ __launch_bounds__(256) void embed_ln_kernel(
    const int* __restrict__ ids, const float* __restrict__ tok,
    const float* __restrict__ pos, const float* __restrict__ w,
    const float* __restrict__ b, float* __restrict__ X, _Float16* __restrict__ Xh)
{
    const int wv_ = threadIdx.x >> 6, lane = threadIdx.x & 63;
    const int tokid = blockIdx.x * 4 + wv_;
    const int s = tokid & (S_ - 1);
    const int id = ids[tokid];
    float4 e = *(const float4*)&tok[id * D_ + lane * 4];
    float4 p = *(const float4*)&pos[s * D_ + lane * 4];
    float4 x = make_float4(e.x + p.x, e.y + p.y, e.z + p.z, e.w + p.w);
    float sum = x.x + x.y + x.z + x.w;
    float sq  = x.x * x.x + x.y * x.y + x.z * x.z + x.w * x.w;
    sum = wave_sum64(sum); sq = wave_sum64(sq);
    float mean = sum * (1.f / D_);
    float var  = sq * (1.f / D_) - mean * mean;
    float rs   = rsqrtf(var + 1e-5f);
    float4 wv = *(const float4*)&w[lane * 4];
    float4 bv = *(const float4*)&b[lane * 4];
    float4 o = make_float4((x.x - mean) * rs * wv.x + bv.x,
                           (x.y - mean) * rs * wv.y + bv.y,
                           (x.z - mean) * rs * wv.z + bv.z,
                           (x.w - mean) * rs * wv.w + bv.w);
    *(float4*)&X[(size_t)tokid * D_ + lane * 4] = o;
    half4 oh = { (_Float16)o.x, (_Float16)o.y, (_Float16)o.z, (_Float16)o.w };
    *(half4*)&Xh[(size_t)tokid * D_ + lane * 4] = oh;
}

// ---------------- fp16 MFMA GEMM, BM=128 BN=64 BK=64, counted vmcnt ----------------
// MODE: 0=f32; 1=fp16+relu; 2=f32+fp16; 3=fp16; 4=f32 with residual add.
template<int MODE>
__global__ __launch_bounds__(256) void gemm_f16(
    const _Float16* __restrict__ A, const _Float16* __restrict__ Bt,
    const float* __restrict__ bias, const float* __restrict__ res,
    float* __restrict__ Cf, _Float16* __restrict__ Ch,
    int K, int N)
{
    __shared__ _Float16 As[2][8192];    // [128][64], source-swizzled
    const int t = threadIdx.x;
    const int wid = t >> 6, lane = t & 63;
    const int wr = wid >> 1, wc = wid & 1;
    const int m0 = blockIdx.x * 128, n0 = blockIdx.y * 64;
    const int li = lane & 15, lg = lane >> 4;
    const int srow = lane >> 3;
    const int scg = (lane & 7) ^ srow;

    f32x4 acc[4][2];
    const f32x4 zf = {0.f, 0.f, 0.f, 0.f};
    #pragma unroll
    for (int mr = 0; mr < 4; ++mr) { acc[mr][0] = zf; acc[mr][1] = zf; }

    const int KT = K >> 6;
    {
        const _Float16* Ab = A + (size_t)m0 * K;
        #pragma unroll
        for (int j = 0; j < 4; ++j) {
            int row = (wid * 4 + j) * 8 + srow;
            GLD16(Ab + (size_t)row * K + scg * 8, &As[0][(wid * 4 + j) * 512]);
        }
    }

    for (int kt = 0; kt < KT; ++kt) {
        const int cur = kt & 1;
        half8 bfr[2][2];
        #pragma unroll
        for (int nr = 0; nr < 2; ++nr) {
            const _Float16* bp = Bt + (size_t)(n0 + wc * 32 + nr * 16 + li) * K + kt * 64 + lg * 8;
            bfr[nr][0] = *(const half8*)bp;
            bfr[nr][1] = *(const half8*)(bp + 32);
        }
        if (kt + 1 < KT) {
            const _Float16* Ab = A + (size_t)m0 * K + (kt + 1) * 64;
            #pragma unroll
            for (int j = 0; j < 4; ++j) {
                int row = (wid * 4 + j) * 8 + srow;
                GLD16(Ab + (size_t)row * K + scg * 8, &As[cur ^ 1][(wid * 4 + j) * 512]);
            }
            asm volatile("s_waitcnt vmcnt(8)" ::: "memory");
        } else {
            asm volatile("s_waitcnt vmcnt(4)" ::: "memory");
        }
        __builtin_amdgcn_s_barrier();
        #pragma unroll
        for (int kk = 0; kk < 2; ++kk) {
            half8 af[4];
            #pragma unroll
            for (int mr = 0; mr < 4; ++mr) {
                int arow = wr * 64 + mr * 16 + li;
                int ablk = (kk * 4 + lg) ^ (li & 7);
                af[mr] = *(const half8*)&As[cur][arow * 64 + ablk * 8];
            }
            #pragma unroll
            for (int mr = 0; mr < 4; ++mr)
                #pragma unroll
                for (int nr = 0; nr < 2; ++nr)
                    acc[mr][nr] = __builtin_amdgcn_mfma_f32_16x16x32_f16(
                        af[mr], bfr[nr][kk], acc[mr][nr], 0, 0, 0);
        }
        __builtin_amdgcn_s_barrier();
    }

    #pragma unroll
    for (int nr = 0; nr < 2; ++nr) {
        const int n = n0 + wc * 32 + nr * 16 + li;
        const float bv = bias[n];
        #pragma unroll
        for (int mr = 0; mr < 4; ++mr) {
            #pragma unroll
            for (int r = 0; r < 4; ++r) {
                const int m = m0 + wr * 64 + mr * 16 + lg * 4 + r;
                float o = acc[mr][nr][r] + bv;
                if (MODE == 1) o = fmaxf(o, 0.f);
                if (MODE == 4) o += res[(size_t)m * N + n];
                if (MODE == 0 || MODE == 2 || MODE == 4) Cf[(size_t)m * N + n] = o;
                if (MODE == 1 || MODE == 2 || MODE == 3) Ch[(size_t)m * N + n] = (_Float16)o;
            }
        }
    }
}

// ---------------- fp16 MFMA GEMM, BM=64 BN=64 BK=64 (2 blocks/CU for small-N) ----------------
template<int MODE>
__global__ __launch_bounds__(256) void gemm64_f16(
    const _Float16* __restrict__ A, const _Float16* __restrict__ Bt,
    const float* __restrict__ bias, const float* __restrict__ res,
    float* __restrict__ Cf, _Float16* __restrict__ Ch,
    int K, int N)
{
    __shared__ _Float16 As[2][4096];    // [64][64], source-swizzled
    const int t = threadIdx.x;
    const int wid = t >> 6, lane = t & 63;
    const int wr = wid >> 1, wc = wid & 1;
    const int m0 = blockIdx.x * 64, n0 = blockIdx.y * 64;
    const int li = lane & 15, lg = lane >> 4;
    const int srow = lane >> 3;
    const int scg = (lane & 7) ^ srow;

    f32x4 acc[2][2];
    const f32x4 zf = {0.f, 0.f, 0.f, 0.f};
    acc[0][0] = zf; acc[0][1] = zf; acc[1][0] = zf; acc[1][1] = zf;

    const int KT = K >> 6;
    {
        const _Float16* Ab = A + (size_t)m0 * K;
        #pragma unroll
        for (int j = 0; j < 2; ++j) {
            int rb = j * 32 + wid * 8;
            GLD16(Ab + (size_t)(rb + srow) * K + scg * 8, &As[0][rb * 64]);
        }
    }

    for (int kt = 0; kt < KT; ++kt) {
        const int cur = kt & 1;
        half8 bfr[2][2];
        #pragma unroll
        for (int nr = 0; nr < 2; ++nr) {
            const _Float16* bp = Bt + (size_t)(n0 + wc * 32 + nr * 16 + li) * K + kt * 64 + lg * 8;
            bfr[nr][0] = *(const half8*)bp;
            bfr[nr][1] = *(const half8*)(bp + 32);
        }
        if (kt + 1 < KT) {
            const _Float16* Ab = A + (size_t)m0 * K + (kt + 1) * 64;
            #pragma unroll
            for (int j = 0; j < 2; ++j) {
                int rb = j * 32 + wid * 8;
                GLD16(Ab + (size_t)(rb + srow) * K + scg * 8, &As[cur ^ 1][rb * 64]);
            }
            asm volatile("s_waitcnt vmcnt(6)" ::: "memory");
        } else {
            asm volatile("s_waitcnt vmcnt(4)" ::: "memory");
        }
        __builtin_amdgcn_s_barrier();
        #pragma unroll
        for (int kk = 0; kk < 2; ++kk) {
            half8 af[2];
            #pragma unroll
            for (int mr = 0; mr < 2; ++mr) {
                int arow = wr * 32 + mr * 16 + li;
                int ablk = (kk * 4 + lg) ^ (li & 7);
                af[mr] = *(const half8*)&As[cur][arow * 64 + ablk * 8];
            }
            #pragma unroll
            for (int mr = 0; mr < 2; ++mr)
                #pragma unroll
                for (int nr = 0; nr < 2; ++nr)
                    acc[mr][nr] = __builtin_amdgcn_mfma_f32_16x16x32_f16(
                        af[mr], bfr[nr][kk], acc[mr][nr], 0, 0, 0);
        }
        __builtin_amdgcn_s_barrier();
    }

    #pragma unroll
    for (int nr = 0; nr < 2; ++nr) {
        const int n = n0 + wc * 32 + nr * 16 + li;
        const float bv = bias[n];
        #pragma unroll
        for (int mr = 0; mr < 2; ++mr) {
            #pragma unroll
            for (int r = 0; r < 4; ++r) {
                const int m = m0 + wr * 32 + mr * 16 + lg * 4 + r;
                float o = acc[mr][nr][r] + bv;
                if (MODE == 1) o = fmaxf(o, 0.f);
                if (MODE == 4) o += res[(size_t)m * N + n];
                if (MODE == 0 || MODE == 2 || MODE == 4) Cf[(size_t)m * N + n] = o;
                if (MODE == 1 || MODE == 2 || MODE == 3) Ch[(size_t)m * N + n] = (_Float16)o;
            }
        }
    }
}

// ---------------- fused Wo GEMM + residual + LayerNorm -> Th fp16 (pipelined) ----------------
// BM=16, BN=256, K=256; A fragments all prefetched; B fragments double-buffered
// so each K-step's L2 latency hides under the previous step's MFMAs.
// Arithmetic identical to the r14 version (which passed at 1.22e-4).
__global__ __launch_bounds__(256) void gemm_wo_ln(
    const _Float16* __restrict__ A,     // ctx fp16 [8192][256]
    const _Float16* __restrict__ Bt,    // WoT fp16 [256][256]
    const float* __restrict__ bias, const float* __restrict__ res,
    const float* __restrict__ lnw, const float* __restrict__ lnb,
    _Float16* __restrict__ Th)
{
    __shared__ float tile[16][260];
    const int t = threadIdx.x;
    const int wid = t >> 6, lane = t & 63;
    const int li = lane & 15, lg = lane >> 4;
    const int m0 = blockIdx.x * 16;

    // prefetch ALL A fragments (4 kt x 2)
    half8 afA[4][2];
    #pragma unroll
    for (int kt = 0; kt < 4; ++kt) {
        const _Float16* ap = A + (size_t)(m0 + li) * 256 + kt * 64 + lg * 8;
        afA[kt][0] = *(const half8*)ap;
        afA[kt][1] = *(const half8*)(ap + 32);
    }

    f32x4 acc[4];
    const f32x4 zf = {0.f, 0.f, 0.f, 0.f};
    #pragma unroll
    for (int nr = 0; nr < 4; ++nr) acc[nr] = zf;

    // double-buffered B fragments: bfA = current, bfB = next
    half8 bfA[4][2], bfB[4][2];
    #pragma unroll
    for (int nr = 0; nr < 4; ++nr) {
        const _Float16* bp = Bt + (size_t)(wid * 64 + nr * 16 + li) * 256 + lg * 8;
        bfA[nr][0] = *(const half8*)bp;
        bfA[nr][1] = *(const half8*)(bp + 32);
    }
    #pragma unroll
    for (int kt = 0; kt < 4; ++kt) {
        // issue next-kt B loads before consuming current
        if (kt < 3) {
            #pragma unroll
            for (int nr = 0; nr < 4; ++nr) {
                const _Float16* bp = Bt + (size_t)(wid * 64 + nr * 16 + li) * 256 + (kt + 1) * 64 + lg * 8;
                bfB[nr][0] = *(const half8*)bp;
                bfB[nr][1] = *(const half8*)(bp + 32);
            }
        }
        #pragma unroll
        for (int nr = 0; nr < 4; ++nr) {
            acc[nr] = __builtin_amdgcn_mfma_f32_16x16x32_f16(afA[kt][0], bfA[nr][0], acc[nr], 0, 0, 0);
            acc[nr] = __builtin_amdgcn_mfma_f32_16x16x32_f16(afA[kt][1], bfA[nr][1], acc[nr], 0, 0, 0);
        }
        // rotate buffers (static unroll -> register renaming, no scratch)
        #pragma unroll
        for (int nr = 0; nr < 4; ++nr) {
            bfA[nr][0] = bfB[nr][0];
            bfA[nr][1] = bfB[nr][1];
        }
    }
    // stage raw acc: row = lg*4+r, col = wid*64+nr*16+li
    #pragma unroll
    for (int nr = 0; nr < 4; ++nr)
        #pragma unroll
        for (int r = 0; r < 4; ++r)
            tile[lg * 4 + r][wid * 64 + nr * 16 + li] = acc[nr][r];
    __syncthreads();

    // phase 2: thread t handles row rr, cols c16*16..c16*16+15
    const int rr = t >> 4, c16 = t & 15;
    float y[16];
    float sum = 0.f, sq = 0.f;
    #pragma unroll
    for (int j4 = 0; j4 < 4; ++j4) {
        const int c = c16 * 16 + j4 * 4;
        float4 rv = *(const float4*)&res[(size_t)(m0 + rr) * 256 + c];
        float4 bv = *(const float4*)&bias[c];
        #pragma unroll
        for (int j = 0; j < 4; ++j) {
            float bb = (j == 0) ? bv.x : (j == 1) ? bv.y : (j == 2) ? bv.z : bv.w;
            float rrv = (j == 0) ? rv.x : (j == 1) ? rv.y : (j == 2) ? rv.z : rv.w;
            float v = tile[rr][c + j] + bb + rrv;
            y[j4 * 4 + j] = v;
            sum += v;
            sq = fmaf(v, v, sq);
        }
    }
    #pragma unroll
    for (int mk = 1; mk <= 8; mk <<= 1) {
        sum += __shfl_xor(sum, mk);
        sq  += __shfl_xor(sq, mk);
    }
    const float mean = sum * (1.f / 256.f);
    const float var  = sq * (1.f / 256.f) - mean * mean;
    const float rs   = rsqrtf(var + 1e-5f);

    #pragma unroll
    for (int h8 = 0; h8 < 2; ++h8) {
        const int c = c16 * 16 + h8 * 8;
        float4 w0 = *(const float4*)&lnw[c];
        float4 w1 = *(const float4*)&lnw[c + 4];
        float4 b0 = *(const float4*)&lnb[c];
        float4 b1 = *(const float4*)&lnb[c + 4];
        half8 o;
        o[0] = (_Float16)((y[h8 * 8 + 0] - mean) * rs * w0.x + b0.x);
        o[1] = (_Float16)((y[h8 * 8 + 1] - mean) * rs * w0.y + b0.y);
        o[2] = (_Float16)((y[h8 * 8 + 2] - mean) * rs * w0.z + b0.z);
        o[3] = (_Float16)((y[h8 * 8 + 3] - mean) * rs * w0.w + b0.w);
        o[4] = (_Float16)((y[h8 * 8 + 4] - mean) * rs * w1.x + b1.x);
        o[5] = (_Float16)((y[h8 * 8 + 5] - mean) * rs * w1.y + b1.y);
        o[6] = (_Float16)((y[h8 * 8 + 6] - mean) * rs * w1.z + b1.z);
        o[7] = (_Float16)((y[h8 * 8 + 7] - mean) * rs * w1.w + b1.w);
        *(half8*)&Th[(size_t)(m0 + rr) * 256 + c] = o;
    }
}

// ---------------- fp16 MFMA flash attention, max-free softmax (r12 version) ----------------
__global__ __launch_bounds__(256, 4) void attn_f16_kernel(
    const _Float16* __restrict__ qkv, const int* __restrict__ ids,
    _Float16* __restrict__ ctxo)
{
    __shared__ unsigned int VTp[2][32 * 38];  // [buf][v][kp] fp16 pairs, stride 38
    __shared__ float maskn[2][64];
    const int t = threadIdx.x;
    const int bh = blockIdx.x, b = bh >> 3, h = bh & 7;
    const int q0 = blockIdx.y * 64;
    const int wid = t >> 6;
    const int lane = t & 63;
    const int i = lane & 15;
    const int g = lane >> 4;
    const int kp = t >> 3;
    const int v0s = (t & 7) * 4;

    const size_t bS = (size_t)b * S_;
    const float scale = 0.17677669529663687f * 1.4426950408889634f;  // 1/sqrt(32)*log2(e)

    const half8 qf = *(const half8*)(qkv + (bS + q0 + wid * 16 + i) * 768 + h * 32 + g * 8);

    float l = 0.f;
    f32x4 cacc[2];
    const f32x4 zf = {0.f, 0.f, 0.f, 0.f};
    cacc[0] = zf; cacc[1] = zf;

    const _Float16* kbase = qkv + 256 + (bS + i) * 768 + h * 32 + g * 8;
    const _Float16* vbase = qkv + 512 + (bS + 2 * kp) * 768 + h * 32 + v0s;

    {
        const ushort* vb = (const ushort*)vbase;
        ushort4 a0 = *(const ushort4*)vb;
        ushort4 a1 = *(const ushort4*)(vb + 768);
        VTp[0][(v0s + 0) * 38 + kp] = (unsigned)a0.x | ((unsigned)a1.x << 16);
        VTp[0][(v0s + 1) * 38 + kp] = (unsigned)a0.y | ((unsigned)a1.y << 16);
        VTp[0][(v0s + 2) * 38 + kp] = (unsigned)a0.z | ((unsigned)a1.z << 16);
        VTp[0][(v0s + 3) * 38 + kp] = (unsigned)a0.w | ((unsigned)a1.w << 16);
        if (t < 64) maskn[0][t] = (ids[bS + t] == 0) ? -1e9f : 0.f;
    }
    f32x4 sc[4];
    #pragma unroll
    for (int c = 0; c < 4; ++c)
        sc[c] = __builtin_amdgcn_mfma_f32_16x16x32_f16(
            *(const half8*)(kbase + c * 16 * 768), qf, zf, 0, 0, 0);

    for (int kt = 0; kt < 16; ++kt) {
        const int cur = kt & 1;
        __syncthreads();
        ushort4 a0, a1;
        int midv = 1;
        half8 kf[4];
        const bool have = (kt < 15);
        if (have) {
            const ushort* vb = (const ushort*)(vbase + (size_t)(kt + 1) * 64 * 768);
            a0 = *(const ushort4*)vb;
            a1 = *(const ushort4*)(vb + 768);
            if (t < 64) midv = ids[bS + (kt + 1) * 64 + t];
            const _Float16* kb = kbase + (size_t)(kt + 1) * 64 * 768;
            #pragma unroll
            for (int c = 0; c < 4; ++c) kf[c] = *(const half8*)(kb + c * 16 * 768);
        }
        float p[4][4];
        float psum = 0.f;
        #pragma unroll
        for (int c = 0; c < 4; ++c) {
            float4 ad = *(const float4*)&maskn[cur][c * 16 + g * 4];
            p[c][0] = exp2f(fmaf(sc[c][0], scale, ad.x));
            p[c][1] = exp2f(fmaf(sc[c][1], scale, ad.y));
            p[c][2] = exp2f(fmaf(sc[c][2], scale, ad.z));
            p[c][3] = exp2f(fmaf(sc[c][3], scale, ad.w));
            psum += (p[c][0] + p[c][1]) + (p[c][2] + p[c][3]);
        }
        l += psum;
        if (have) {
            #pragma unroll
            for (int c = 0; c < 4; ++c)
                sc[c] = __builtin_amdgcn_mfma_f32_16x16x32_f16(kf[c], qf, zf, 0, 0, 0);
        }
        if (have) {
            VTp[cur ^ 1][(v0s + 0) * 38 + kp] = (unsigned)a0.x | ((unsigned)a1.x << 16);
            VTp[cur ^ 1][(v0s + 1) * 38 + kp] = (unsigned)a0.y | ((unsigned)a1.y << 16);
            VTp[cur ^ 1][(v0s + 2) * 38 + kp] = (unsigned)a0.z | ((unsigned)a1.z << 16);
            VTp[cur ^ 1][(v0s + 3) * 38 + kp] = (unsigned)a0.w | ((unsigned)a1.w << 16);
            if (t < 64) maskn[cur ^ 1][t] = (midv == 0) ? -1e9f : 0.f;
        }
        #pragma unroll
        for (int c = 0; c < 4; ++c) {
            half2v plo = __builtin_bit_cast(half2v, __builtin_amdgcn_cvt_pkrtz(p[c][0], p[c][1]));
            half2v phi = __builtin_bit_cast(half2v, __builtin_amdgcn_cvt_pkrtz(p[c][2], p[c][3]));
            half4 pb = { plo[0], plo[1], phi[0], phi[1] };
            #pragma unroll
            for (int vh = 0; vh < 2; ++vh) {
                const unsigned int* vp = &VTp[cur][(vh * 16 + i) * 38 + 8 * c + 2 * g];
                unsigned long long vv = *(const unsigned long long*)vp;
                half4 vf = __builtin_bit_cast(half4, vv);
                cacc[vh] = __builtin_amdgcn_mfma_f32_16x16x16f16(vf, pb, cacc[vh], 0, 0, 0);
            }
        }
    }
    l += __shfl_xor(l, 16);
    l += __shfl_xor(l, 32);
    const float inv = 1.f / l;
    _Float16* crow = ctxo + (bS + q0 + wid * 16 + i) * 256 + h * 32;
    #pragma unroll
    for (int vh = 0; vh < 2; ++vh) {
        half4 st;
        #pragma unroll
        for (int r = 0; r < 4; ++r) st[r] = (_Float16)(cacc[vh][r] * inv);
        *(half4*)&crow[vh * 16 + g * 4] = st;
    }
}

// ---------------- parallel classifier head ----------------
__global__ __launch_bounds__(256) void head1_kernel(
    const float* __restrict__ X, const float* __restrict__ ft1w,
    const float* __restrict__ ft1b, float* __restrict__ h1)
{
    __shared__ float clsS[8][256];
    __shared__ float ps[8][8][32];   // [dgroup][b][n]
    const int t = threadIdx.x;
    #pragma unroll
    for (int b = 0; b < 8; ++b) clsS[b][t] = X[(size_t)b * S_ * D_ + t];
    __syncthreads();
    const int n = t & 31, dg = t >> 5;
    const int gn = blockIdx.x * 32 + n;
    float s[8] = {};
    for (int dd = 0; dd < 32; ++dd) {
        int d = dg * 32 + dd;
        float w = ft1w[d * 256 + gn];
        #pragma unroll
        for (int b = 0; b < 8; ++b) s[b] = fmaf(clsS[b][d], w, s[b]);
    }
    #pragma unroll
    for (int b = 0; b < 8; ++b) ps[dg][b][n] = s[b];
    __syncthreads();
    {
        const int b = t >> 5, nn = t & 31;
        float a = 0.f;
        #pragma unroll
        for (int g = 0; g < 8; ++g) a += ps[g][b][nn];
        const int gn2 = blockIdx.x * 32 + nn;
        h1[b * 256 + gn2] = fmaxf(a + ft1b[gn2], 0.f);
    }
}

__global__ __launch_bounds__(256) void head2_kernel(
    const float* __restrict__ h1, const float* __restrict__ ft2w,
    const float* __restrict__ ft2b, float* __restrict__ featW,
    float* __restrict__ out)
{
    __shared__ float hS[8][256];
    __shared__ float ps[8][8][32];
    const int t = threadIdx.x;
    #pragma unroll
    for (int b = 0; b < 8; ++b) hS[b][t] = h1[b * 256 + t];
    __syncthreads();
    const int n = t & 31, dg = t >> 5;
    const int gn = blockIdx.x * 32 + n;
    float s[8] = {};
    for (int dd = 0; dd < 32; ++dd) {
        int d = dg * 32 + dd;
        float w = ft2w[d * 128 + gn];
        #pragma unroll
        for (int b = 0; b < 8; ++b) s[b] = fmaf(hS[b][d], w, s[b]);
    }
    #pragma unroll
    for (int b = 0; b < 8; ++b) ps[dg][b][n] = s[b];
    __syncthreads();
    {
        const int b = t >> 5, nn = t & 31;
        float a = 0.f;
        #pragma unroll
        for (int g = 0; g < 8; ++g) a += ps[g][b][nn];
        const int gn2 = blockIdx.x * 32 + nn;
        float v = a + ft2b[gn2];
        featW[b * 128 + gn2] = v;
        out[16 + b * 128 + gn2] = v;
    }
}

__global__ __launch_bounds__(64) void head3_kernel(
    const float* __restrict__ featW, const float* __restrict__ clw,
    const float* __restrict__ clb, float* __restrict__ out)
{
    const int t = threadIdx.x;
    if (t < 16) {
        const int b = t >> 1, c = t & 1;
        float s = 0.f;
        for (int d = 0; d < 128; ++d) s = fmaf(featW[b * 128 + d], clw[d * 2 + c], s);
        out[t] = s + clb[c];
    }
}

extern "C" void kernel_launch(void* const* d_in, const int* in_sizes, int n_in,
                              void* d_out, int out_size, void* d_ws, size_t ws_size,
                              hipStream_t stream)
{
    const int*   ids  = (const int*)d_in[0];
    const float* tok  = (const float*)d_in[1];
    const float* pos  = (const float*)d_in[2];
    const float* elnw = (const float*)d_in[3];
    const float* elnb = (const float*)d_in[4];
    const float* Wq   = (const float*)d_in[5];
    const float* bq   = (const float*)d_in[6];
    const float* Wk   = (const float*)d_in[7];
    const float* bk   = (const float*)d_in[8];
    const float* Wv   = (const float*)d_in[9];
    const float* bv   = (const float*)d_in[10];
    const float* Wo   = (const float*)d_in[11];
    const float* bo   = (const float*)d_in[12];
    const float* lnw  = (const float*)d_in[13];
    const float* lnb  = (const float*)d_in[14];
    const float* W1   = (const float*)d_in[15];
    const float* b1   = (const float*)d_in[16];
    const float* W2   = (const float*)d_in[17];
    const float* b2   = (const float*)d_in[18];
    const float* ft1w = (const float*)d_in[19];
    const float* ft1b = (const float*)d_in[20];
    const float* ft2w = (const float*)d_in[21];
    const float* ft2b = (const float*)d_in[22];
    const float* clw  = (const float*)d_in[23];
    const float* clb  = (const float*)d_in[24];
    float* out = (float*)d_out;

    char* ws = (char*)d_ws;
    float*    X    = (float*)(ws);                          // 8 MB
    _Float16* Xh   = (_Float16*)(ws + (16ull << 20));       // 4 MB
    _Float16* Th   = (_Float16*)(ws + (20ull << 20));       // 4 MB
    _Float16* qkvb = (_Float16*)(ws + (24ull << 20));       // 12 MB
    _Float16* ctx  = (_Float16*)(ws + (36ull << 20));       // 4 MB
    _Float16* Hb   = (_Float16*)(ws + (24ull << 20));       // 16 MB (reuses qkv+ctx)
    _Float16* qkvT = (_Float16*)(ws + (40ull << 20));       // 1.5 MB
    _Float16* WoT  = (_Float16*)(ws + (42ull << 20));       // 0.5 MB
    _Float16* W1T  = (_Float16*)(ws + (43ull << 20));       // 2 MB
    _Float16* W2T  = (_Float16*)(ws + (45ull << 20));       // 2 MB
    float*    bqkv = (float*)(ws + (47ull << 20));          // 12 KB
    float*    h1W  = (float*)(ws + (47ull << 20) + (16ull << 10));  // 8 KB
    float*    feW  = (float*)(ws + (47ull << 20) + (24ull << 10));  // 4 KB

    // ---- weight prep ----
    transpose_qkv<<<dim3(8, 8, 12), 256, 0, stream>>>(Wq, Wk, Wv, qkvT);
    transpose_cvt<<<dim3(8, 8, 4),  256, 0, stream>>>(Wo, WoT, 256, 256);
    transpose_cvt<<<dim3(32, 8, 4), 256, 0, stream>>>(W1, W1T, 256, 1024);
    transpose_cvt<<<dim3(8, 32, 4), 256, 0, stream>>>(W2, W2T, 1024, 256);
    pack_bias<<<12, 256, 0, stream>>>(bq, bk, bv, bqkv);

    embed_ln_kernel<<<2048, 256, 0, stream>>>(ids, tok, pos, elnw, elnb, X, Xh);

    for (int i = 0; i < 4; ++i) {
        gemm_f16<3><<<dim3(64, 12), 256, 0, stream>>>(
            Xh, qkvT + (size_t)i * 196608, bqkv + i * 768, nullptr, nullptr, qkvb, 256, 768);
        attn_f16_kernel<<<dim3(64, 16), 256, 0, stream>>>(qkvb, ids, ctx);
        gemm_wo_ln<<<512, 256, 0, stream>>>(
            ctx, WoT + (size_t)i * 65536, bo + i * 256, X,
            lnw + i * 256, lnb + i * 256, Th);
        gemm_f16<1><<<dim3(64, 16), 256, 0, stream>>>(
            Th, W1T + (size_t)i * 262144, b1 + i * 1024, nullptr, nullptr, Hb, 256, 1024);
        gemm64_f16<2><<<dim3(128, 4), 256, 0, stream>>>(
            Hb, W2T + (size_t)i * 262144, b2 + i * 256, nullptr, X, Xh, 1024, 256);
    }

    head1_kernel<<<8, 256, 0, stream>>>(X, ft1w, ft1b, h1W);
    head2_kernel<<<4, 256, 0, stream>>>(h1W, ft2w, ft2b, feW, out);
    head3_kernel<<<1, 64, 0, stream>>>(feW, clw, clb, out);
}

// Round 16
// 420.001 us; speedup vs baseline: 1.0544x; 1.0544x over previous
//
#include <hip/hip_runtime.h>
#include <math.h>

#define S_ 1024
#define D_ 256

typedef __attribute__((ext_vector_type(8))) _Float16 half8;
typedef __attribute__((ext_vector_type(4))) _Float16 half4;
typedef __attribute__((ext_vector_type(2))) _Float16 half2v;
typedef __attribute__((ext_vector_type(4))) float f32x4;
typedef __attribute__((ext_vector_type(4))) unsigned int u32x4;

__device__ __forceinline__ float wave_sum64(float x) {
    x += __shfl_xor(x, 32); x += __shfl_xor(x, 16); x += __shfl_xor(x, 8);
    x += __shfl_xor(x, 4);  x += __shfl_xor(x, 2);  x += __shfl_xor(x, 1);
    return x;
}

#define GLD16(gp, lp) __builtin_amdgcn_global_load_lds( \
    (const __attribute__((address_space(1))) void*)(gp), \
    (__attribute__((address_space(3))) void*)(lp), 16, 0, 0)

// ---------------- unified weight prep: ONE launch ----------------
// blocks [0,768): qkv transpose  (12 units x 8x8 tiles, 256x256 each)
// blocks [768,1024): Wo transpose (4 layers x 8x8)
// blocks [1024,2048): W1 transpose (4 layers x 32x8, K=256 N=1024)
// blocks [2048,3072): W2 transpose (4 layers x 8x32, K=1024 N=256)
// blocks [3072,3084): qkv bias pack
__global__ __launch_bounds__(256) void prep_all(
    const float* __restrict__ Wq, const float* __restrict__ Wk,
    const float* __restrict__ Wv, const float* __restrict__ Wo,
    const float* __restrict__ W1, const float* __restrict__ W2,
    const float* __restrict__ bq, const float* __restrict__ bk,
    const float* __restrict__ bv,
    _Float16* __restrict__ qkvT, _Float16* __restrict__ WoT,
    _Float16* __restrict__ W1T,  _Float16* __restrict__ W2T,
    float* __restrict__ bqkv)
{
    const int id = blockIdx.x;
    const int t = threadIdx.x;
    if (id >= 3072) {                       // bias pack
        const int idx = id - 3072, l = idx / 3, m = idx % 3;
        const float* s = (m == 0 ? bq : (m == 1 ? bk : bv)) + l * 256;
        bqkv[l * 768 + m * 256 + t] = s[t];
        return;
    }
    const float* src; _Float16* dst; int K, N, bxi, byi;
    if (id < 768) {                         // qkv
        const int u = id >> 6, rem = id & 63, l = u / 3, m = u % 3;
        src = (m == 0 ? Wq : (m == 1 ? Wk : Wv)) + (size_t)l * 65536;
        dst = qkvT + (size_t)l * 196608 + (size_t)m * 65536;
        K = 256; N = 256; bxi = rem & 7; byi = rem >> 3;
    } else if (id < 1024) {                 // Wo
        const int idx = id - 768, z = idx >> 6, rem = idx & 63;
        src = Wo + (size_t)z * 65536; dst = WoT + (size_t)z * 65536;
        K = 256; N = 256; bxi = rem & 7; byi = rem >> 3;
    } else if (id < 2048) {                 // W1: K=256 N=1024, grid (32,8)
        const int idx = id - 1024, z = idx >> 8, rem = idx & 255;
        src = W1 + (size_t)z * 262144; dst = W1T + (size_t)z * 262144;
        K = 256; N = 1024; bxi = rem & 31; byi = rem >> 5;
    } else {                                // W2: K=1024 N=256, grid (8,32)
        const int idx = id - 2048, z = idx >> 8, rem = idx & 255;
        src = W2 + (size_t)z * 262144; dst = W2T + (size_t)z * 262144;
        K = 1024; N = 256; bxi = rem & 7; byi = rem >> 3;
    }
    __shared__ float tile[32][33];
    const int bx = bxi * 32, by = byi * 32;
    const int c = t & 31, r0 = t >> 5;
    #pragma unroll
    for (int j = 0; j < 4; ++j)
        tile[r0 + 8 * j][c] = src[(size_t)(by + r0 + 8 * j) * N + bx + c];
    __syncthreads();
    #pragma unroll
    for (int j = 0; j < 4; ++j)
        dst[(size_t)(bx + r0 + 8 * j) * K + by + c] = (_Float16)tile[c][r0 + 8 * j];
}

// ---------------- embed + LN (4 tokens per 256-thr block) ----------------
__global__ __launch_bounds__(256) void embed_ln_kernel(
    const int* __restrict__ ids, const float* __restrict__ tok,
    const float* __restrict__ pos, const float* __restrict__ w,
    const float* __restrict__ b, float* __restrict__ X, _Float16* __restrict__ Xh)
{
    const int wv_ = threadIdx.x >> 6, lane = threadIdx.x & 63;
    const int tokid = blockIdx.x * 4 + wv_;
    const int s = tokid & (S_ - 1);
    const int id = ids[tokid];
    float4 e = *(const float4*)&tok[id * D_ + lane * 4];
    float4 p = *(const float4*)&pos[s * D_ + lane * 4];
    float4 x = make_float4(e.x + p.x, e.y + p.y, e.z + p.z, e.w + p.w);
    float sum = x.x + x.y + x.z + x.w;
    float sq  = x.x * x.x + x.y * x.y + x.z * x.z + x.w * x.w;
    sum = wave_sum64(sum); sq = wave_sum64(sq);
    float mean = sum * (1.f / D_);
    float var  = sq * (1.f / D_) - mean * mean;
    float rs   = rsqrtf(var + 1e-5f);
    float4 wv = *(const float4*)&w[lane * 4];
    float4 bv = *(const float4*)&b[lane * 4];
    float4 o = make_float4((x.x - mean) * rs * wv.x + bv.x,
                           (x.y - mean) * rs * wv.y + bv.y,
                           (x.z - mean) * rs * wv.z + bv.z,
                           (x.w - mean) * rs * wv.w + bv.w);
    *(float4*)&X[(size_t)tokid * D_ + lane * 4] = o;
    half4 oh = { (_Float16)o.x, (_Float16)o.y, (_Float16)o.z, (_Float16)o.w };
    *(half4*)&Xh[(size_t)tokid * D_ + lane * 4] = oh;
}

// ---------------- LN (residual already added) -> fp16 ----------------
__global__ __launch_bounds__(256) void ln_kernel(
    const float* __restrict__ Y, const float* __restrict__ w,
    const float* __restrict__ b, _Float16* __restrict__ Th)
{
    const int wv_ = threadIdx.x >> 6, lane = threadIdx.x & 63;
    const int tokid = blockIdx.x * 4 + wv_;
    const size_t base = (size_t)tokid * D_ + lane * 4;
    float4 x = *(const float4*)&Y[base];
    float sum = x.x + x.y + x.z + x.w;
    float sq  = x.x * x.x + x.y * x.y + x.z * x.z + x.w * x.w;
    sum = wave_sum64(sum); sq = wave_sum64(sq);
    float mean = sum * (1.f / D_);
    float var  = sq * (1.f / D_) - mean * mean;
    float rs   = rsqrtf(var + 1e-5f);
    float4 wv = *(const float4*)&w[lane * 4];
    float4 bv = *(const float4*)&b[lane * 4];
    half4 oh = { (_Float16)((x.x - mean) * rs * wv.x + bv.x),
                 (_Float16)((x.y - mean) * rs * wv.y + bv.y),
                 (_Float16)((x.z - mean) * rs * wv.z + bv.z),
                 (_Float16)((x.w - mean) * rs * wv.w + bv.w) };
    *(half4*)&Th[base] = oh;
}

// ---------------- fp16 MFMA GEMM, BM=128 BN=64 BK=64, counted vmcnt ----------------
// MODE: 0=f32; 1=fp16+relu; 2=f32+fp16; 3=fp16; 4=f32 with residual add.
template<int MODE>
__global__ __launch_bounds__(256) void gemm_f16(
    const _Float16* __restrict__ A, const _Float16* __restrict__ Bt,
    const float* __restrict__ bias, const float* __restrict__ res,
    float* __restrict__ Cf, _Float16* __restrict__ Ch,
    int K, int N)
{
    __shared__ _Float16 As[2][8192];    // [128][64], source-swizzled
    const int t = threadIdx.x;
    const int wid = t >> 6, lane = t & 63;
    const int wr = wid >> 1, wc = wid & 1;
    const int m0 = blockIdx.x * 128, n0 = blockIdx.y * 64;
    const int li = lane & 15, lg = lane >> 4;
    const int srow = lane >> 3;
    const int scg = (lane & 7) ^ srow;

    f32x4 acc[4][2];
    const f32x4 zf = {0.f, 0.f, 0.f, 0.f};
    #pragma unroll
    for (int mr = 0; mr < 4; ++mr) { acc[mr][0] = zf; acc[mr][1] = zf; }

    const int KT = K >> 6;
    {
        const _Float16* Ab = A + (size_t)m0 * K;
        #pragma unroll
        for (int j = 0; j < 4; ++j) {
            int row = (wid * 4 + j) * 8 + srow;
            GLD16(Ab + (size_t)row * K + scg * 8, &As[0][(wid * 4 + j) * 512]);
        }
    }

    for (int kt = 0; kt < KT; ++kt) {
        const int cur = kt & 1;
        half8 bfr[2][2];
        #pragma unroll
        for (int nr = 0; nr < 2; ++nr) {
            const _Float16* bp = Bt + (size_t)(n0 + wc * 32 + nr * 16 + li) * K + kt * 64 + lg * 8;
            bfr[nr][0] = *(const half8*)bp;
            bfr[nr][1] = *(const half8*)(bp + 32);
        }
        if (kt + 1 < KT) {
            const _Float16* Ab = A + (size_t)m0 * K + (kt + 1) * 64;
            #pragma unroll
            for (int j = 0; j < 4; ++j) {
                int row = (wid * 4 + j) * 8 + srow;
                GLD16(Ab + (size_t)row * K + scg * 8, &As[cur ^ 1][(wid * 4 + j) * 512]);
            }
            asm volatile("s_waitcnt vmcnt(8)" ::: "memory");
        } else {
            asm volatile("s_waitcnt vmcnt(4)" ::: "memory");
        }
        __builtin_amdgcn_s_barrier();
        #pragma unroll
        for (int kk = 0; kk < 2; ++kk) {
            half8 af[4];
            #pragma unroll
            for (int mr = 0; mr < 4; ++mr) {
                int arow = wr * 64 + mr * 16 + li;
                int ablk = (kk * 4 + lg) ^ (li & 7);
                af[mr] = *(const half8*)&As[cur][arow * 64 + ablk * 8];
            }
            #pragma unroll
            for (int mr = 0; mr < 4; ++mr)
                #pragma unroll
                for (int nr = 0; nr < 2; ++nr)
                    acc[mr][nr] = __builtin_amdgcn_mfma_f32_16x16x32_f16(
                        af[mr], bfr[nr][kk], acc[mr][nr], 0, 0, 0);
        }
        __builtin_amdgcn_s_barrier();
    }

    #pragma unroll
    for (int nr = 0; nr < 2; ++nr) {
        const int n = n0 + wc * 32 + nr * 16 + li;
        const float bv = bias[n];
        #pragma unroll
        for (int mr = 0; mr < 4; ++mr) {
            #pragma unroll
            for (int r = 0; r < 4; ++r) {
                const int m = m0 + wr * 64 + mr * 16 + lg * 4 + r;
                float o = acc[mr][nr][r] + bv;
                if (MODE == 1) o = fmaxf(o, 0.f);
                if (MODE == 4) o += res[(size_t)m * N + n];
                if (MODE == 0 || MODE == 2 || MODE == 4) Cf[(size_t)m * N + n] = o;
                if (MODE == 1 || MODE == 2 || MODE == 3) Ch[(size_t)m * N + n] = (_Float16)o;
            }
        }
    }
}

// ---------------- fp16 MFMA GEMM, BM=64 BN=64 BK=64 (2 blocks/CU for small-N) ----------------
template<int MODE>
__global__ __launch_bounds__(256) void gemm64_f16(
    const _Float16* __restrict__ A, const _Float16* __restrict__ Bt,
    const float* __restrict__ bias, const float* __restrict__ res,
    float* __restrict__ Cf, _Float16* __restrict__ Ch,
    int K, int N)
{
    __shared__ _Float16 As[2][4096];    // [64][64], source-swizzled
    const int t = threadIdx.x;
    const int wid = t >> 6, lane = t & 63;
    const int wr = wid >> 1, wc = wid & 1;
    const int m0 = blockIdx.x * 64, n0 = blockIdx.y * 64;
    const int li = lane & 15, lg = lane >> 4;
    const int srow = lane >> 3;
    const int scg = (lane & 7) ^ srow;

    f32x4 acc[2][2];
    const f32x4 zf = {0.f, 0.f, 0.f, 0.f};
    acc[0][0] = zf; acc[0][1] = zf; acc[1][0] = zf; acc[1][1] = zf;

    const int KT = K >> 6;
    {
        const _Float16* Ab = A + (size_t)m0 * K;
        #pragma unroll
        for (int j = 0; j < 2; ++j) {
            int rb = j * 32 + wid * 8;
            GLD16(Ab + (size_t)(rb + srow) * K + scg * 8, &As[0][rb * 64]);
        }
    }

    for (int kt = 0; kt < KT; ++kt) {
        const int cur = kt & 1;
        half8 bfr[2][2];
        #pragma unroll
        for (int nr = 0; nr < 2; ++nr) {
            const _Float16* bp = Bt + (size_t)(n0 + wc * 32 + nr * 16 + li) * K + kt * 64 + lg * 8;
            bfr[nr][0] = *(const half8*)bp;
            bfr[nr][1] = *(const half8*)(bp + 32);
        }
        if (kt + 1 < KT) {
            const _Float16* Ab = A + (size_t)m0 * K + (kt + 1) * 64;
            #pragma unroll
            for (int j = 0; j < 2; ++j) {
                int rb = j * 32 + wid * 8;
                GLD16(Ab + (size_t)(rb + srow) * K + scg * 8, &As[cur ^ 1][rb * 64]);
            }
            asm volatile("s_waitcnt vmcnt(6)" ::: "memory");
        } else {
            asm volatile("s_waitcnt vmcnt(4)" ::: "memory");
        }
        __builtin_amdgcn_s_barrier();
        #pragma unroll
        for (int kk = 0; kk < 2; ++kk) {
            half8 af[2];
            #pragma unroll
            for (int mr = 0; mr < 2; ++mr) {
                int arow = wr * 32 + mr * 16 + li;
                int ablk = (kk * 4 + lg) ^ (li & 7);
                af[mr] = *(const half8*)&As[cur][arow * 64 + ablk * 8];
            }
            #pragma unroll
            for (int mr = 0; mr < 2; ++mr)
                #pragma unroll
                for (int nr = 0; nr < 2; ++nr)
                    acc[mr][nr] = __builtin_amdgcn_mfma_f32_16x16x32_f16(
                        af[mr], bfr[nr][kk], acc[mr][nr], 0, 0, 0);
        }
        __builtin_amdgcn_s_barrier();
    }

    #pragma unroll
    for (int nr = 0; nr < 2; ++nr) {
        const int n = n0 + wc * 32 + nr * 16 + li;
        const float bv = bias[n];
        #pragma unroll
        for (int mr = 0; mr < 2; ++mr) {
            #pragma unroll
            for (int r = 0; r < 4; ++r) {
                const int m = m0 + wr * 32 + mr * 16 + lg * 4 + r;
                float o = acc[mr][nr][r] + bv;
                if (MODE == 1) o = fmaxf(o, 0.f);
                if (MODE == 4) o += res[(size_t)m * N + n];
                if (MODE == 0 || MODE == 2 || MODE == 4) Cf[(size_t)m * N + n] = o;
                if (MODE == 1 || MODE == 2 || MODE == 3) Ch[(size_t)m * N + n] = (_Float16)o;
            }
        }
    }
}

// ---------------- fp16 MFMA flash attention, max-free softmax (r12 version) ----------------
__global__ __launch_bounds__(256, 4) void attn_f16_kernel(
    const _Float16* __restrict__ qkv, const int* __restrict__ ids,
    _Float16* __restrict__ ctxo)
{
    __shared__ unsigned int VTp[2][32 * 38];  // [buf][v][kp] fp16 pairs, stride 38
    __shared__ float maskn[2][64];
    const int t = threadIdx.x;
    const int bh = blockIdx.x, b = bh >> 3, h = bh & 7;
    const int q0 = blockIdx.y * 64;
    const int wid = t >> 6;
    const int lane = t & 63;
    const int i = lane & 15;
    const int g = lane >> 4;
    const int kp = t >> 3;
    const int v0s = (t & 7) * 4;

    const size_t bS = (size_t)b * S_;
    const float scale = 0.17677669529663687f * 1.4426950408889634f;  // 1/sqrt(32)*log2(e)

    const half8 qf = *(const half8*)(qkv + (bS + q0 + wid * 16 + i) * 768 + h * 32 + g * 8);

    float l = 0.f;
    f32x4 cacc[2];
    const f32x4 zf = {0.f, 0.f, 0.f, 0.f};
    cacc[0] = zf; cacc[1] = zf;

    const _Float16* kbase = qkv + 256 + (bS + i) * 768 + h * 32 + g * 8;
    const _Float16* vbase = qkv + 512 + (bS + 2 * kp) * 768 + h * 32 + v0s;

    {
        const ushort* vb = (const ushort*)vbase;
        ushort4 a0 = *(const ushort4*)vb;
        ushort4 a1 = *(const ushort4*)(vb + 768);
        VTp[0][(v0s + 0) * 38 + kp] = (unsigned)a0.x | ((unsigned)a1.x << 16);
        VTp[0][(v0s + 1) * 38 + kp] = (unsigned)a0.y | ((unsigned)a1.y << 16);
        VTp[0][(v0s + 2) * 38 + kp] = (unsigned)a0.z | ((unsigned)a1.z << 16);
        VTp[0][(v0s + 3) * 38 + kp] = (unsigned)a0.w | ((unsigned)a1.w << 16);
        if (t < 64) maskn[0][t] = (ids[bS + t] == 0) ? -1e9f : 0.f;
    }
    f32x4 sc[4];
    #pragma unroll
    for (int c = 0; c < 4; ++c)
        sc[c] = __builtin_amdgcn_mfma_f32_16x16x32_f16(
            *(const half8*)(kbase + c * 16 * 768), qf, zf, 0, 0, 0);

    for (int kt = 0; kt < 16; ++kt) {
        const int cur = kt & 1;
        __syncthreads();
        ushort4 a0, a1;
        int midv = 1;
        half8 kf[4];
        const bool have = (kt < 15);
        if (have) {
            const ushort* vb = (const ushort*)(vbase + (size_t)(kt + 1) * 64 * 768);
            a0 = *(const ushort4*)vb;
            a1 = *(const ushort4*)(vb + 768);
            if (t < 64) midv = ids[bS + (kt + 1) * 64 + t];
            const _Float16* kb = kbase + (size_t)(kt + 1) * 64 * 768;
            #pragma unroll
            for (int c = 0; c < 4; ++c) kf[c] = *(const half8*)(kb + c * 16 * 768);
        }
        float p[4][4];
        float psum = 0.f;
        #pragma unroll
        for (int c = 0; c < 4; ++c) {
            float4 ad = *(const float4*)&maskn[cur][c * 16 + g * 4];
            p[c][0] = exp2f(fmaf(sc[c][0], scale, ad.x));
            p[c][1] = exp2f(fmaf(sc[c][1], scale, ad.y));
            p[c][2] = exp2f(fmaf(sc[c][2], scale, ad.z));
            p[c][3] = exp2f(fmaf(sc[c][3], scale, ad.w));
            psum += (p[c][0] + p[c][1]) + (p[c][2] + p[c][3]);
        }
        l += psum;
        if (have) {
            #pragma unroll
            for (int c = 0; c < 4; ++c)
                sc[c] = __builtin_amdgcn_mfma_f32_16x16x32_f16(kf[c], qf, zf, 0, 0, 0);
        }
        if (have) {
            VTp[cur ^ 1][(v0s + 0) * 38 + kp] = (unsigned)a0.x | ((unsigned)a1.x << 16);
            VTp[cur ^ 1][(v0s + 1) * 38 + kp] = (unsigned)a0.y | ((unsigned)a1.y << 16);
            VTp[cur ^ 1][(v0s + 2) * 38 + kp] = (unsigned)a0.z | ((unsigned)a1.z << 16);
            VTp[cur ^ 1][(v0s + 3) * 38 + kp] = (unsigned)a0.w | ((unsigned)a1.w << 16);
            if (t < 64) maskn[cur ^ 1][t] = (midv == 0) ? -1e9f : 0.f;
        }
        #pragma unroll
        for (int c = 0; c < 4; ++c) {
            half2v plo = __builtin_bit_cast(half2v, __builtin_amdgcn_cvt_pkrtz(p[c][0], p[c][1]));
            half2v phi = __builtin_bit_cast(half2v, __builtin_amdgcn_cvt_pkrtz(p[c][2], p[c][3]));
            half4 pb = { plo[0], plo[1], phi[0], phi[1] };
            #pragma unroll
            for (int vh = 0; vh < 2; ++vh) {
                const unsigned int* vp = &VTp[cur][(vh * 16 + i) * 38 + 8 * c + 2 * g];
                unsigned long long vv = *(const unsigned long long*)vp;
                half4 vf = __builtin_bit_cast(half4, vv);
                cacc[vh] = __builtin_amdgcn_mfma_f32_16x16x16f16(vf, pb, cacc[vh], 0, 0, 0);
            }
        }
    }
    l += __shfl_xor(l, 16);
    l += __shfl_xor(l, 32);
    const float inv = 1.f / l;
    _Float16* crow = ctxo + (bS + q0 + wid * 16 + i) * 256 + h * 32;
    #pragma unroll
    for (int vh = 0; vh < 2; ++vh) {
        half4 st;
        #pragma unroll
        for (int r = 0; r < 4; ++r) st[r] = (_Float16)(cacc[vh][r] * inv);
        *(half4*)&crow[vh * 16 + g * 4] = st;
    }
}

// ---------------- parallel classifier head ----------------
__global__ __launch_bounds__(256) void head1_kernel(
    const float* __restrict__ X, const float* __restrict__ ft1w,
    const float* __restrict__ ft1b, float* __restrict__ h1)
{
    __shared__ float clsS[8][256];
    __shared__ float ps[8][8][32];   // [dgroup][b][n]
    const int t = threadIdx.x;
    #pragma unroll
    for (int b = 0; b < 8; ++b) clsS[b][t] = X[(size_t)b * S_ * D_ + t];
    __syncthreads();
    const int n = t & 31, dg = t >> 5;
    const int gn = blockIdx.x * 32 + n;
    float s[8] = {};
    for (int dd = 0; dd < 32; ++dd) {
        int d = dg * 32 + dd;
        float w = ft1w[d * 256 + gn];
        #pragma unroll
        for (int b = 0; b < 8; ++b) s[b] = fmaf(clsS[b][d], w, s[b]);
    }
    #pragma unroll
    for (int b = 0; b < 8; ++b) ps[dg][b][n] = s[b];
    __syncthreads();
    {
        const int b = t >> 5, nn = t & 31;
        float a = 0.f;
        #pragma unroll
        for (int g = 0; g < 8; ++g) a += ps[g][b][nn];
        const int gn2 = blockIdx.x * 32 + nn;
        h1[b * 256 + gn2] = fmaxf(a + ft1b[gn2], 0.f);
    }
}

__global__ __launch_bounds__(256) void head2_kernel(
    const float* __restrict__ h1, const float* __restrict__ ft2w,
    const float* __restrict__ ft2b, float* __restrict__ featW,
    float* __restrict__ out)
{
    __shared__ float hS[8][256];
    __shared__ float ps[8][8][32];
    const int t = threadIdx.x;
    #pragma unroll
    for (int b = 0; b < 8; ++b) hS[b][t] = h1[b * 256 + t];
    __syncthreads();
    const int n = t & 31, dg = t >> 5;
    const int gn = blockIdx.x * 32 + n;
    float s[8] = {};
    for (int dd = 0; dd < 32; ++dd) {
        int d = dg * 32 + dd;
        float w = ft2w[d * 128 + gn];
        #pragma unroll
        for (int b = 0; b < 8; ++b) s[b] = fmaf(hS[b][d], w, s[b]);
    }
    #pragma unroll
    for (int b = 0; b < 8; ++b) ps[dg][b][n] = s[b];
    __syncthreads();
    {
        const int b = t >> 5, nn = t & 31;
        float a = 0.f;
        #pragma unroll
        for (int g = 0; g < 8; ++g) a += ps[g][b][nn];
        const int gn2 = blockIdx.x * 32 + nn;
        float v = a + ft2b[gn2];
        featW[b * 128 + gn2] = v;
        out[16 + b * 128 + gn2] = v;
    }
}

__global__ __launch_bounds__(64) void head3_kernel(
    const float* __restrict__ featW, const float* __restrict__ clw,
    const float* __restrict__ clb, float* __restrict__ out)
{
    const int t = threadIdx.x;
    if (t < 16) {
        const int b = t >> 1, c = t & 1;
        float s = 0.f;
        for (int d = 0; d < 128; ++d) s = fmaf(featW[b * 128 + d], clw[d * 2 + c], s);
        out[t] = s + clb[c];
    }
}

extern "C" void kernel_launch(void* const* d_in, const int* in_sizes, int n_in,
                              void* d_out, int out_size, void* d_ws, size_t ws_size,
                              hipStream_t stream)
{
    const int*   ids  = (const int*)d_in[0];
    const float* tok  = (const float*)d_in[1];
    const float* pos  = (const float*)d_in[2];
    const float* elnw = (const float*)d_in[3];
    const float* elnb = (const float*)d_in[4];
    const float* Wq   = (const float*)d_in[5];
    const float* bq   = (const float*)d_in[6];
    const float* Wk   = (const float*)d_in[7];
    const float* bk   = (const float*)d_in[8];
    const float* Wv   = (const float*)d_in[9];
    const float* bv   = (const float*)d_in[10];
    const float* Wo   = (const float*)d_in[11];
    const float* bo   = (const float*)d_in[12];
    const float* lnw  = (const float*)d_in[13];
    const float* lnb  = (const float*)d_in[14];
    const float* W1   = (const float*)d_in[15];
    const float* b1   = (const float*)d_in[16];
    const float* W2   = (const float*)d_in[17];
    const float* b2   = (const float*)d_in[18];
    const float* ft1w = (const float*)d_in[19];
    const float* ft1b = (const float*)d_in[20];
    const float* ft2w = (const float*)d_in[21];
    const float* ft2b = (const float*)d_in[22];
    const float* clw  = (const float*)d_in[23];
    const float* clb  = (const float*)d_in[24];
    float* out = (float*)d_out;

    char* ws = (char*)d_ws;
    float*    X    = (float*)(ws);                          // 8 MB
    float*    Y    = (float*)(ws + (8ull << 20));           // 8 MB
    _Float16* Xh   = (_Float16*)(ws + (16ull << 20));       // 4 MB
    _Float16* Th   = (_Float16*)(ws + (20ull << 20));       // 4 MB
    _Float16* qkvb = (_Float16*)(ws + (24ull << 20));       // 12 MB
    _Float16* ctx  = (_Float16*)(ws + (36ull << 20));       // 4 MB
    _Float16* Hb   = (_Float16*)(ws + (24ull << 20));       // 16 MB (reuses qkv+ctx)
    _Float16* qkvT = (_Float16*)(ws + (40ull << 20));       // 1.5 MB
    _Float16* WoT  = (_Float16*)(ws + (42ull << 20));       // 0.5 MB
    _Float16* W1T  = (_Float16*)(ws + (43ull << 20));       // 2 MB
    _Float16* W2T  = (_Float16*)(ws + (45ull << 20));       // 2 MB
    float*    bqkv = (float*)(ws + (47ull << 20));          // 12 KB
    float*    h1W  = (float*)(ws + (47ull << 20) + (16ull << 10));  // 8 KB
    float*    feW  = (float*)(ws + (47ull << 20) + (24ull << 10));  // 4 KB

    // ---- weight prep: single launch ----
    prep_all<<<3084, 256, 0, stream>>>(Wq, Wk, Wv, Wo, W1, W2, bq, bk, bv,
                                       qkvT, WoT, W1T, W2T, bqkv);

    embed_ln_kernel<<<2048, 256, 0, stream>>>(ids, tok, pos, elnw, elnb, X, Xh);

    for (int i = 0; i < 4; ++i) {
        gemm_f16<3><<<dim3(64, 12), 256, 0, stream>>>(
            Xh, qkvT + (size_t)i * 196608, bqkv + i * 768, nullptr, nullptr, qkvb, 256, 768);
        attn_f16_kernel<<<dim3(64, 16), 256, 0, stream>>>(qkvb, ids, ctx);
        gemm64_f16<4><<<dim3(128, 4), 256, 0, stream>>>(
            ctx, WoT + (size_t)i * 65536, bo + i * 256, X, Y, nullptr, 256, 256);
        ln_kernel<<<2048, 256, 0, stream>>>(Y, lnw + i * 256, lnb + i * 256, Th);
        gemm_f16<1><<<dim3(64, 16), 256, 0, stream>>>(
            Th, W1T + (size_t)i * 262144, b1 + i * 1024, nullptr, nullptr, Hb, 256, 1024);
        gemm64_f16<2><<<dim3(128, 4), 256, 0, stream>>>(
            Hb, W2T + (size_t)i * 262144, b2 + i * 256, nullptr, X, Xh, 1024, 256);
    }

    head1_kernel<<<8, 256, 0, stream>>>(X, ft1w, ft1b, h1W);
    head2_kernel<<<4, 256, 0, stream>>>(h1W, ft2w, ft2b, feW, out);
    head3_kernel<<<1, 64, 0, stream>>>(feW, clw, clb, out);
}

// Round 17
// 416.957 us; speedup vs baseline: 1.0621x; 1.0073x over previous
//
#include <hip/hip_runtime.h>
#include <math.h>

#define S_ 1024
#define D_ 256

typedef __attribute__((ext_vector_type(8))) _Float16 half8;
typedef __attribute__((ext_vector_type(4))) _Float16 half4;
typedef __attribute__((ext_vector_type(2))) _Float16 half2v;
typedef __attribute__((ext_vector_type(4))) float f32x4;
typedef __attribute__((ext_vector_type(4))) unsigned int u32x4;

__device__ __forceinline__ float wave_sum64(float x) {
    x += __shfl_xor(x, 32); x += __shfl_xor(x, 16); x += __shfl_xor(x, 8);
    x += __shfl_xor(x, 4);  x += __shfl_xor(x, 2);  x += __shfl_xor(x, 1);
    return x;
}

#define GLD16(gp, lp) __builtin_amdgcn_global_load_lds( \
    (const __attribute__((address_space(1))) void*)(gp), \
    (__attribute__((address_space(3))) void*)(lp), 16, 0, 0)

// ---------------- unified weight prep: ONE launch ----------------
__global__ __launch_bounds__(256) void prep_all(
    const float* __restrict__ Wq, const float* __restrict__ Wk,
    const float* __restrict__ Wv, const float* __restrict__ Wo,
    const float* __restrict__ W1, const float* __restrict__ W2,
    const float* __restrict__ bq, const float* __restrict__ bk,
    const float* __restrict__ bv,
    _Float16* __restrict__ qkvT, _Float16* __restrict__ WoT,
    _Float16* __restrict__ W1T,  _Float16* __restrict__ W2T,
    float* __restrict__ bqkv)
{
    const int id = blockIdx.x;
    const int t = threadIdx.x;
    if (id >= 3072) {                       // bias pack
        const int idx = id - 3072, l = idx / 3, m = idx % 3;
        const float* s = (m == 0 ? bq : (m == 1 ? bk : bv)) + l * 256;
        bqkv[l * 768 + m * 256 + t] = s[t];
        return;
    }
    const float* src; _Float16* dst; int K, N, bxi, byi;
    if (id < 768) {                         // qkv
        const int u = id >> 6, rem = id & 63, l = u / 3, m = u % 3;
        src = (m == 0 ? Wq : (m == 1 ? Wk : Wv)) + (size_t)l * 65536;
        dst = qkvT + (size_t)l * 196608 + (size_t)m * 65536;
        K = 256; N = 256; bxi = rem & 7; byi = rem >> 3;
    } else if (id < 1024) {                 // Wo
        const int idx = id - 768, z = idx >> 6, rem = idx & 63;
        src = Wo + (size_t)z * 65536; dst = WoT + (size_t)z * 65536;
        K = 256; N = 256; bxi = rem & 7; byi = rem >> 3;
    } else if (id < 2048) {                 // W1: K=256 N=1024
        const int idx = id - 1024, z = idx >> 8, rem = idx & 255;
        src = W1 + (size_t)z * 262144; dst = W1T + (size_t)z * 262144;
        K = 256; N = 1024; bxi = rem & 31; byi = rem >> 5;
    } else {                                // W2: K=1024 N=256
        const int idx = id - 2048, z = idx >> 8, rem = idx & 255;
        src = W2 + (size_t)z * 262144; dst = W2T + (size_t)z * 262144;
        K = 1024; N = 256; bxi = rem & 7; byi = rem >> 3;
    }
    __shared__ float tile[32][33];
    const int bx = bxi * 32, by = byi * 32;
    const int c = t & 31, r0 = t >> 5;
    #pragma unroll
    for (int j = 0; j < 4; ++j)
        tile[r0 + 8 * j][c] = src[(size_t)(by + r0 + 8 * j) * N + bx + c];
    __syncthreads();
    #pragma unroll
    for (int j = 0; j < 4; ++j)
        dst[(size_t)(bx + r0 + 8 * j) * K + by + c] = (_Float16)tile[c][r0 + 8 * j];
}

// ---------------- embed + LN (4 tokens per 256-thr block) ----------------
__global__ __launch_bounds__(256) void embed_ln_kernel(
    const int* __restrict__ ids, const float* __restrict__ tok,
    const float* __restrict__ pos, const float* __restrict__ w,
    const float* __restrict__ b, float* __restrict__ X, _Float16* __restrict__ Xh)
{
    const int wv_ = threadIdx.x >> 6, lane = threadIdx.x & 63;
    const int tokid = blockIdx.x * 4 + wv_;
    const int s = tokid & (S_ - 1);
    const int id = ids[tokid];
    float4 e = *(const float4*)&tok[id * D_ + lane * 4];
    float4 p = *(const float4*)&pos[s * D_ + lane * 4];
    float4 x = make_float4(e.x + p.x, e.y + p.y, e.z + p.z, e.w + p.w);
    float sum = x.x + x.y + x.z + x.w;
    float sq  = x.x * x.x + x.y * x.y + x.z * x.z + x.w * x.w;
    sum = wave_sum64(sum); sq = wave_sum64(sq);
    float mean = sum * (1.f / D_);
    float var  = sq * (1.f / D_) - mean * mean;
    float rs   = rsqrtf(var + 1e-5f);
    float4 wv = *(const float4*)&w[lane * 4];
    float4 bv = *(const float4*)&b[lane * 4];
    float4 o = make_float4((x.x - mean) * rs * wv.x + bv.x,
                           (x.y - mean) * rs * wv.y + bv.y,
                           (x.z - mean) * rs * wv.z + bv.z,
                           (x.w - mean) * rs * wv.w + bv.w);
    *(float4*)&X[(size_t)tokid * D_ + lane * 4] = o;
    half4 oh = { (_Float16)o.x, (_Float16)o.y, (_Float16)o.z, (_Float16)o.w };
    *(half4*)&Xh[(size_t)tokid * D_ + lane * 4] = oh;
}

// ---------------- LN (residual already added) -> fp16 ----------------
__global__ __launch_bounds__(256) void ln_kernel(
    const float* __restrict__ Y, const float* __restrict__ w,
    const float* __restrict__ b, _Float16* __restrict__ Th)
{
    const int wv_ = threadIdx.x >> 6, lane = threadIdx.x & 63;
    const int tokid = blockIdx.x * 4 + wv_;
    const size_t base = (size_t)tokid * D_ + lane * 4;
    float4 x = *(const float4*)&Y[base];
    float sum = x.x + x.y + x.z + x.w;
    float sq  = x.x * x.x + x.y * x.y + x.z * x.z + x.w * x.w;
    sum = wave_sum64(sum); sq = wave_sum64(sq);
    float mean = sum * (1.f / D_);
    float var  = sq * (1.f / D_) - mean * mean;
    float rs   = rsqrtf(var + 1e-5f);
    float4 wv = *(const float4*)&w[lane * 4];
    float4 bv = *(const float4*)&b[lane * 4];
    half4 oh = { (_Float16)((x.x - mean) * rs * wv.x + bv.x),
                 (_Float16)((x.y - mean) * rs * wv.y + bv.y),
                 (_Float16)((x.z - mean) * rs * wv.z + bv.z),
                 (_Float16)((x.w - mean) * rs * wv.w + bv.w) };
    *(half4*)&Th[base] = oh;
}

// ---------------- fp16 MFMA GEMM, BM=128 BN=64 BK=64, counted vmcnt ----------------
// MODE: 0=f32; 1=fp16+relu; 2=f32+fp16; 3=fp16; 4=f32 with residual add.
template<int MODE>
__global__ __launch_bounds__(256) void gemm_f16(
    const _Float16* __restrict__ A, const _Float16* __restrict__ Bt,
    const float* __restrict__ bias, const float* __restrict__ res,
    float* __restrict__ Cf, _Float16* __restrict__ Ch,
    int K, int N)
{
    __shared__ _Float16 As[2][8192];    // [128][64], source-swizzled
    const int t = threadIdx.x;
    const int wid = t >> 6, lane = t & 63;
    const int wr = wid >> 1, wc = wid & 1;
    const int m0 = blockIdx.x * 128, n0 = blockIdx.y * 64;
    const int li = lane & 15, lg = lane >> 4;
    const int srow = lane >> 3;
    const int scg = (lane & 7) ^ srow;

    f32x4 acc[4][2];
    const f32x4 zf = {0.f, 0.f, 0.f, 0.f};
    #pragma unroll
    for (int mr = 0; mr < 4; ++mr) { acc[mr][0] = zf; acc[mr][1] = zf; }

    const int KT = K >> 6;
    {
        const _Float16* Ab = A + (size_t)m0 * K;
        #pragma unroll
        for (int j = 0; j < 4; ++j) {
            int row = (wid * 4 + j) * 8 + srow;
            GLD16(Ab + (size_t)row * K + scg * 8, &As[0][(wid * 4 + j) * 512]);
        }
    }

    for (int kt = 0; kt < KT; ++kt) {
        const int cur = kt & 1;
        half8 bfr[2][2];
        #pragma unroll
        for (int nr = 0; nr < 2; ++nr) {
            const _Float16* bp = Bt + (size_t)(n0 + wc * 32 + nr * 16 + li) * K + kt * 64 + lg * 8;
            bfr[nr][0] = *(const half8*)bp;
            bfr[nr][1] = *(const half8*)(bp + 32);
        }
        if (kt + 1 < KT) {
            const _Float16* Ab = A + (size_t)m0 * K + (kt + 1) * 64;
            #pragma unroll
            for (int j = 0; j < 4; ++j) {
                int row = (wid * 4 + j) * 8 + srow;
                GLD16(Ab + (size_t)row * K + scg * 8, &As[cur ^ 1][(wid * 4 + j) * 512]);
            }
            asm volatile("s_waitcnt vmcnt(8)" ::: "memory");
        } else {
            asm volatile("s_waitcnt vmcnt(4)" ::: "memory");
        }
        __builtin_amdgcn_s_barrier();
        #pragma unroll
        for (int kk = 0; kk < 2; ++kk) {
            half8 af[4];
            #pragma unroll
            for (int mr = 0; mr < 4; ++mr) {
                int arow = wr * 64 + mr * 16 + li;
                int ablk = (kk * 4 + lg) ^ (li & 7);
                af[mr] = *(const half8*)&As[cur][arow * 64 + ablk * 8];
            }
            #pragma unroll
            for (int mr = 0; mr < 4; ++mr)
                #pragma unroll
                for (int nr = 0; nr < 2; ++nr)
                    acc[mr][nr] = __builtin_amdgcn_mfma_f32_16x16x32_f16(
                        af[mr], bfr[nr][kk], acc[mr][nr], 0, 0, 0);
        }
        __builtin_amdgcn_s_barrier();
    }

    #pragma unroll
    for (int nr = 0; nr < 2; ++nr) {
        const int n = n0 + wc * 32 + nr * 16 + li;
        const float bv = bias[n];
        #pragma unroll
        for (int mr = 0; mr < 4; ++mr) {
            #pragma unroll
            for (int r = 0; r < 4; ++r) {
                const int m = m0 + wr * 64 + mr * 16 + lg * 4 + r;
                float o = acc[mr][nr][r] + bv;
                if (MODE == 1) o = fmaxf(o, 0.f);
                if (MODE == 4) o += res[(size_t)m * N + n];
                if (MODE == 0 || MODE == 2 || MODE == 4) Cf[(size_t)m * N + n] = o;
                if (MODE == 1 || MODE == 2 || MODE == 3) Ch[(size_t)m * N + n] = (_Float16)o;
            }
        }
    }
}

// ---------------- fp16 MFMA GEMM, BM=128 BN=128 BK=64 (wide: W1) ----------------
// Wave tile 64x64, 32 MFMA per K-step; fp16+relu output only (MODE 1 semantics).
__global__ __launch_bounds__(256, 2) void gemm_f16w(
    const _Float16* __restrict__ A, const _Float16* __restrict__ Bt,
    const float* __restrict__ bias, _Float16* __restrict__ Ch,
    int K, int N)
{
    __shared__ _Float16 As[2][8192];    // [128][64], source-swizzled
    const int t = threadIdx.x;
    const int wid = t >> 6, lane = t & 63;
    const int wr = wid >> 1, wc = wid & 1;
    const int m0 = blockIdx.x * 128, n0 = blockIdx.y * 128;
    const int li = lane & 15, lg = lane >> 4;
    const int srow = lane >> 3;
    const int scg = (lane & 7) ^ srow;

    f32x4 acc[4][4];
    const f32x4 zf = {0.f, 0.f, 0.f, 0.f};
    #pragma unroll
    for (int mr = 0; mr < 4; ++mr)
        #pragma unroll
        for (int nr = 0; nr < 4; ++nr) acc[mr][nr] = zf;

    const int KT = K >> 6;
    {
        const _Float16* Ab = A + (size_t)m0 * K;
        #pragma unroll
        for (int j = 0; j < 4; ++j) {
            int row = (wid * 4 + j) * 8 + srow;
            GLD16(Ab + (size_t)row * K + scg * 8, &As[0][(wid * 4 + j) * 512]);
        }
    }

    for (int kt = 0; kt < KT; ++kt) {
        const int cur = kt & 1;
        half8 bfr[4][2];
        #pragma unroll
        for (int nr = 0; nr < 4; ++nr) {
            const _Float16* bp = Bt + (size_t)(n0 + wc * 64 + nr * 16 + li) * K + kt * 64 + lg * 8;
            bfr[nr][0] = *(const half8*)bp;
            bfr[nr][1] = *(const half8*)(bp + 32);
        }
        if (kt + 1 < KT) {
            const _Float16* Ab = A + (size_t)m0 * K + (kt + 1) * 64;
            #pragma unroll
            for (int j = 0; j < 4; ++j) {
                int row = (wid * 4 + j) * 8 + srow;
                GLD16(Ab + (size_t)row * K + scg * 8, &As[cur ^ 1][(wid * 4 + j) * 512]);
            }
            asm volatile("s_waitcnt vmcnt(12)" ::: "memory");   // 8 B-loads + 4 next-stage
        } else {
            asm volatile("s_waitcnt vmcnt(8)" ::: "memory");    // 8 B-loads
        }
        __builtin_amdgcn_s_barrier();
        #pragma unroll
        for (int kk = 0; kk < 2; ++kk) {
            half8 af[4];
            #pragma unroll
            for (int mr = 0; mr < 4; ++mr) {
                int arow = wr * 64 + mr * 16 + li;
                int ablk = (kk * 4 + lg) ^ (li & 7);
                af[mr] = *(const half8*)&As[cur][arow * 64 + ablk * 8];
            }
            #pragma unroll
            for (int mr = 0; mr < 4; ++mr)
                #pragma unroll
                for (int nr = 0; nr < 4; ++nr)
                    acc[mr][nr] = __builtin_amdgcn_mfma_f32_16x16x32_f16(
                        af[mr], bfr[nr][kk], acc[mr][nr], 0, 0, 0);
        }
        __builtin_amdgcn_s_barrier();
    }

    #pragma unroll
    for (int nr = 0; nr < 4; ++nr) {
        const int n = n0 + wc * 64 + nr * 16 + li;
        const float bv = bias[n];
        #pragma unroll
        for (int mr = 0; mr < 4; ++mr) {
            #pragma unroll
            for (int r = 0; r < 4; ++r) {
                const int m = m0 + wr * 64 + mr * 16 + lg * 4 + r;
                float o = fmaxf(acc[mr][nr][r] + bv, 0.f);
                Ch[(size_t)m * N + n] = (_Float16)o;
            }
        }
    }
}

// ---------------- fp16 MFMA GEMM, BM=64 BN=64 BK=64 (2 blocks/CU for small-N) ----------------
template<int MODE>
__global__ __launch_bounds__(256) void gemm64_f16(
    const _Float16* __restrict__ A, const _Float16* __restrict__ Bt,
    const float* __restrict__ bias, const float* __restrict__ res,
    float* __restrict__ Cf, _Float16* __restrict__ Ch,
    int K, int N)
{
    __shared__ _Float16 As[2][4096];    // [64][64], source-swizzled
    const int t = threadIdx.x;
    const int wid = t >> 6, lane = t & 63;
    const int wr = wid >> 1, wc = wid & 1;
    const int m0 = blockIdx.x * 64, n0 = blockIdx.y * 64;
    const int li = lane & 15, lg = lane >> 4;
    const int srow = lane >> 3;
    const int scg = (lane & 7) ^ srow;

    f32x4 acc[2][2];
    const f32x4 zf = {0.f, 0.f, 0.f, 0.f};
    acc[0][0] = zf; acc[0][1] = zf; acc[1][0] = zf; acc[1][1] = zf;

    const int KT = K >> 6;
    {
        const _Float16* Ab = A + (size_t)m0 * K;
        #pragma unroll
        for (int j = 0; j < 2; ++j) {
            int rb = j * 32 + wid * 8;
            GLD16(Ab + (size_t)(rb + srow) * K + scg * 8, &As[0][rb * 64]);
        }
    }

    for (int kt = 0; kt < KT; ++kt) {
        const int cur = kt & 1;
        half8 bfr[2][2];
        #pragma unroll
        for (int nr = 0; nr < 2; ++nr) {
            const _Float16* bp = Bt + (size_t)(n0 + wc * 32 + nr * 16 + li) * K + kt * 64 + lg * 8;
            bfr[nr][0] = *(const half8*)bp;
            bfr[nr][1] = *(const half8*)(bp + 32);
        }
        if (kt + 1 < KT) {
            const _Float16* Ab = A + (size_t)m0 * K + (kt + 1) * 64;
            #pragma unroll
            for (int j = 0; j < 2; ++j) {
                int rb = j * 32 + wid * 8;
                GLD16(Ab + (size_t)(rb + srow) * K + scg * 8, &As[cur ^ 1][rb * 64]);
            }
            asm volatile("s_waitcnt vmcnt(6)" ::: "memory");
        } else {
            asm volatile("s_waitcnt vmcnt(4)" ::: "memory");
        }
        __builtin_amdgcn_s_barrier();
        #pragma unroll
        for (int kk = 0; kk < 2; ++kk) {
            half8 af[2];
            #pragma unroll
            for (int mr = 0; mr < 2; ++mr) {
                int arow = wr * 32 + mr * 16 + li;
                int ablk = (kk * 4 + lg) ^ (li & 7);
                af[mr] = *(const half8*)&As[cur][arow * 64 + ablk * 8];
            }
            #pragma unroll
            for (int mr = 0; mr < 2; ++mr)
                #pragma unroll
                for (int nr = 0; nr < 2; ++nr)
                    acc[mr][nr] = __builtin_amdgcn_mfma_f32_16x16x32_f16(
                        af[mr], bfr[nr][kk], acc[mr][nr], 0, 0, 0);
        }
        __builtin_amdgcn_s_barrier();
    }

    #pragma unroll
    for (int nr = 0; nr < 2; ++nr) {
        const int n = n0 + wc * 32 + nr * 16 + li;
        const float bv = bias[n];
        #pragma unroll
        for (int mr = 0; mr < 2; ++mr) {
            #pragma unroll
            for (int r = 0; r < 4; ++r) {
                const int m = m0 + wr * 32 + mr * 16 + lg * 4 + r;
                float o = acc[mr][nr][r] + bv;
                if (MODE == 1) o = fmaxf(o, 0.f);
                if (MODE == 4) o += res[(size_t)m * N + n];
                if (MODE == 0 || MODE == 2 || MODE == 4) Cf[(size_t)m * N + n] = o;
                if (MODE == 1 || MODE == 2 || MODE == 3) Ch[(size_t)m * N + n] = (_Float16)o;
            }
        }
    }
}

// ---------------- fp16 MFMA flash attention, max-free softmax (r12 version) ----------------
__global__ __launch_bounds__(256, 4) void attn_f16_kernel(
    const _Float16* __restrict__ qkv, const int* __restrict__ ids,
    _Float16* __restrict__ ctxo)
{
    __shared__ unsigned int VTp[2][32 * 38];  // [buf][v][kp] fp16 pairs, stride 38
    __shared__ float maskn[2][64];
    const int t = threadIdx.x;
    const int bh = blockIdx.x, b = bh >> 3, h = bh & 7;
    const int q0 = blockIdx.y * 64;
    const int wid = t >> 6;
    const int lane = t & 63;
    const int i = lane & 15;
    const int g = lane >> 4;
    const int kp = t >> 3;
    const int v0s = (t & 7) * 4;

    const size_t bS = (size_t)b * S_;
    const float scale = 0.17677669529663687f * 1.4426950408889634f;  // 1/sqrt(32)*log2(e)

    const half8 qf = *(const half8*)(qkv + (bS + q0 + wid * 16 + i) * 768 + h * 32 + g * 8);

    float l = 0.f;
    f32x4 cacc[2];
    const f32x4 zf = {0.f, 0.f, 0.f, 0.f};
    cacc[0] = zf; cacc[1] = zf;

    const _Float16* kbase = qkv + 256 + (bS + i) * 768 + h * 32 + g * 8;
    const _Float16* vbase = qkv + 512 + (bS + 2 * kp) * 768 + h * 32 + v0s;

    {
        const ushort* vb = (const ushort*)vbase;
        ushort4 a0 = *(const ushort4*)vb;
        ushort4 a1 = *(const ushort4*)(vb + 768);
        VTp[0][(v0s + 0) * 38 + kp] = (unsigned)a0.x | ((unsigned)a1.x << 16);
        VTp[0][(v0s + 1) * 38 + kp] = (unsigned)a0.y | ((unsigned)a1.y << 16);
        VTp[0][(v0s + 2) * 38 + kp] = (unsigned)a0.z | ((unsigned)a1.z << 16);
        VTp[0][(v0s + 3) * 38 + kp] = (unsigned)a0.w | ((unsigned)a1.w << 16);
        if (t < 64) maskn[0][t] = (ids[bS + t] == 0) ? -1e9f : 0.f;
    }
    f32x4 sc[4];
    #pragma unroll
    for (int c = 0; c < 4; ++c)
        sc[c] = __builtin_amdgcn_mfma_f32_16x16x32_f16(
            *(const half8*)(kbase + c * 16 * 768), qf, zf, 0, 0, 0);

    for (int kt = 0; kt < 16; ++kt) {
        const int cur = kt & 1;
        __syncthreads();
        ushort4 a0, a1;
        int midv = 1;
        half8 kf[4];
        const bool have = (kt < 15);
        if (have) {
            const ushort* vb = (const ushort*)(vbase + (size_t)(kt + 1) * 64 * 768);
            a0 = *(const ushort4*)vb;
            a1 = *(const ushort4*)(vb + 768);
            if (t < 64) midv = ids[bS + (kt + 1) * 64 + t];
            const _Float16* kb = kbase + (size_t)(kt + 1) * 64 * 768;
            #pragma unroll
            for (int c = 0; c < 4; ++c) kf[c] = *(const half8*)(kb + c * 16 * 768);
        }
        float p[4][4];
        float psum = 0.f;
        #pragma unroll
        for (int c = 0; c < 4; ++c) {
            float4 ad = *(const float4*)&maskn[cur][c * 16 + g * 4];
            p[c][0] = exp2f(fmaf(sc[c][0], scale, ad.x));
            p[c][1] = exp2f(fmaf(sc[c][1], scale, ad.y));
            p[c][2] = exp2f(fmaf(sc[c][2], scale, ad.z));
            p[c][3] = exp2f(fmaf(sc[c][3], scale, ad.w));
            psum += (p[c][0] + p[c][1]) + (p[c][2] + p[c][3]);
        }
        l += psum;
        if (have) {
            #pragma unroll
            for (int c = 0; c < 4; ++c)
                sc[c] = __builtin_amdgcn_mfma_f32_16x16x32_f16(kf[c], qf, zf, 0, 0, 0);
        }
        if (have) {
            VTp[cur ^ 1][(v0s + 0) * 38 + kp] = (unsigned)a0.x | ((unsigned)a1.x << 16);
            VTp[cur ^ 1][(v0s + 1) * 38 + kp] = (unsigned)a0.y | ((unsigned)a1.y << 16);
            VTp[cur ^ 1][(v0s + 2) * 38 + kp] = (unsigned)a0.z | ((unsigned)a1.z << 16);
            VTp[cur ^ 1][(v0s + 3) * 38 + kp] = (unsigned)a0.w | ((unsigned)a1.w << 16);
            if (t < 64) maskn[cur ^ 1][t] = (midv == 0) ? -1e9f : 0.f;
        }
        #pragma unroll
        for (int c = 0; c < 4; ++c) {
            half2v plo = __builtin_bit_cast(half2v, __builtin_amdgcn_cvt_pkrtz(p[c][0], p[c][1]));
            half2v phi = __builtin_bit_cast(half2v, __builtin_amdgcn_cvt_pkrtz(p[c][2], p[c][3]));
            half4 pb = { plo[0], plo[1], phi[0], phi[1] };
            #pragma unroll
            for (int vh = 0; vh < 2; ++vh) {
                const unsigned int* vp = &VTp[cur][(vh * 16 + i) * 38 + 8 * c + 2 * g];
                unsigned long long vv = *(const unsigned long long*)vp;
                half4 vf = __builtin_bit_cast(half4, vv);
                cacc[vh] = __builtin_amdgcn_mfma_f32_16x16x16f16(vf, pb, cacc[vh], 0, 0, 0);
            }
        }
    }
    l += __shfl_xor(l, 16);
    l += __shfl_xor(l, 32);
    const float inv = 1.f / l;
    _Float16* crow = ctxo + (bS + q0 + wid * 16 + i) * 256 + h * 32;
    #pragma unroll
    for (int vh = 0; vh < 2; ++vh) {
        half4 st;
        #pragma unroll
        for (int r = 0; r < 4; ++r) st[r] = (_Float16)(cacc[vh][r] * inv);
        *(half4*)&crow[vh * 16 + g * 4] = st;
    }
}

// ---------------- parallel classifier head ----------------
__global__ __launch_bounds__(256) void head1_kernel(
    const float* __restrict__ X, const float* __restrict__ ft1w,
    const float* __restrict__ ft1b, float* __restrict__ h1)
{
    __shared__ float clsS[8][256];
    __shared__ float ps[8][8][32];   // [dgroup][b][n]
    const int t = threadIdx.x;
    #pragma unroll
    for (int b = 0; b < 8; ++b) clsS[b][t] = X[(size_t)b * S_ * D_ + t];
    __syncthreads();
    const int n = t & 31, dg = t >> 5;
    const int gn = blockIdx.x * 32 + n;
    float s[8] = {};
    for (int dd = 0; dd < 32; ++dd) {
        int d = dg * 32 + dd;
        float w = ft1w[d * 256 + gn];
        #pragma unroll
        for (int b = 0; b < 8; ++b) s[b] = fmaf(clsS[b][d], w, s[b]);
    }
    #pragma unroll
    for (int b = 0; b < 8; ++b) ps[dg][b][n] = s[b];
    __syncthreads();
    {
        const int b = t >> 5, nn = t & 31;
        float a = 0.f;
        #pragma unroll
        for (int g = 0; g < 8; ++g) a += ps[g][b][nn];
        const int gn2 = blockIdx.x * 32 + nn;
        h1[b * 256 + gn2] = fmaxf(a + ft1b[gn2], 0.f);
    }
}

__global__ __launch_bounds__(256) void head2_kernel(
    const float* __restrict__ h1, const float* __restrict__ ft2w,
    const float* __restrict__ ft2b, float* __restrict__ featW,
    float* __restrict__ out)
{
    __shared__ float hS[8][256];
    __shared__ float ps[8][8][32];
    const int t = threadIdx.x;
    #pragma unroll
    for (int b = 0; b < 8; ++b) hS[b][t] = h1[b * 256 + t];
    __syncthreads();
    const int n = t & 31, dg = t >> 5;
    const int gn = blockIdx.x * 32 + n;
    float s[8] = {};
    for (int dd = 0; dd < 32; ++dd) {
        int d = dg * 32 + dd;
        float w = ft2w[d * 128 + gn];
        #pragma unroll
        for (int b = 0; b < 8; ++b) s[b] = fmaf(hS[b][d], w, s[b]);
    }
    #pragma unroll
    for (int b = 0; b < 8; ++b) ps[dg][b][n] = s[b];
    __syncthreads();
    {
        const int b = t >> 5, nn = t & 31;
        float a = 0.f;
        #pragma unroll
        for (int g = 0; g < 8; ++g) a += ps[g][b][nn];
        const int gn2 = blockIdx.x * 32 + nn;
        float v = a + ft2b[gn2];
        featW[b * 128 + gn2] = v;
        out[16 + b * 128 + gn2] = v;
    }
}

__global__ __launch_bounds__(64) void head3_kernel(
    const float* __restrict__ featW, const float* __restrict__ clw,
    const float* __restrict__ clb, float* __restrict__ out)
{
    const int t = threadIdx.x;
    if (t < 16) {
        const int b = t >> 1, c = t & 1;
        float s = 0.f;
        for (int d = 0; d < 128; ++d) s = fmaf(featW[b * 128 + d], clw[d * 2 + c], s);
        out[t] = s + clb[c];
    }
}

extern "C" void kernel_launch(void* const* d_in, const int* in_sizes, int n_in,
                              void* d_out, int out_size, void* d_ws, size_t ws_size,
                              hipStream_t stream)
{
    const int*   ids  = (const int*)d_in[0];
    const float* tok  = (const float*)d_in[1];
    const float* pos  = (const float*)d_in[2];
    const float* elnw = (const float*)d_in[3];
    const float* elnb = (const float*)d_in[4];
    const float* Wq   = (const float*)d_in[5];
    const float* bq   = (const float*)d_in[6];
    const float* Wk   = (const float*)d_in[7];
    const float* bk   = (const float*)d_in[8];
    const float* Wv   = (const float*)d_in[9];
    const float* bv   = (const float*)d_in[10];
    const float* Wo   = (const float*)d_in[11];
    const float* bo   = (const float*)d_in[12];
    const float* lnw  = (const float*)d_in[13];
    const float* lnb  = (const float*)d_in[14];
    const float* W1   = (const float*)d_in[15];
    const float* b1   = (const float*)d_in[16];
    const float* W2   = (const float*)d_in[17];
    const float* b2   = (const float*)d_in[18];
    const float* ft1w = (const float*)d_in[19];
    const float* ft1b = (const float*)d_in[20];
    const float* ft2w = (const float*)d_in[21];
    const float* ft2b = (const float*)d_in[22];
    const float* clw  = (const float*)d_in[23];
    const float* clb  = (const float*)d_in[24];
    float* out = (float*)d_out;

    char* ws = (char*)d_ws;
    float*    X    = (float*)(ws);                          // 8 MB
    float*    Y    = (float*)(ws + (8ull << 20));           // 8 MB
    _Float16* Xh   = (_Float16*)(ws + (16ull << 20));       // 4 MB
    _Float16* Th   = (_Float16*)(ws + (20ull << 20));       // 4 MB
    _Float16* qkvb = (_Float16*)(ws + (24ull << 20));       // 12 MB
    _Float16* ctx  = (_Float16*)(ws + (36ull << 20));       // 4 MB
    _Float16* Hb   = (_Float16*)(ws + (24ull << 20));       // 16 MB (reuses qkv+ctx)
    _Float16* qkvT = (_Float16*)(ws + (40ull << 20));       // 1.5 MB
    _Float16* WoT  = (_Float16*)(ws + (42ull << 20));       // 0.5 MB
    _Float16* W1T  = (_Float16*)(ws + (43ull << 20));       // 2 MB
    _Float16* W2T  = (_Float16*)(ws + (45ull << 20));       // 2 MB
    float*    bqkv = (float*)(ws + (47ull << 20));          // 12 KB
    float*    h1W  = (float*)(ws + (47ull << 20) + (16ull << 10));  // 8 KB
    float*    feW  = (float*)(ws + (47ull << 20) + (24ull << 10));  // 4 KB

    // ---- weight prep: single launch ----
    prep_all<<<3084, 256, 0, stream>>>(Wq, Wk, Wv, Wo, W1, W2, bq, bk, bv,
                                       qkvT, WoT, W1T, W2T, bqkv);

    embed_ln_kernel<<<2048, 256, 0, stream>>>(ids, tok, pos, elnw, elnb, X, Xh);

    for (int i = 0; i < 4; ++i) {
        gemm_f16<3><<<dim3(64, 12), 256, 0, stream>>>(
            Xh, qkvT + (size_t)i * 196608, bqkv + i * 768, nullptr, nullptr, qkvb, 256, 768);
        attn_f16_kernel<<<dim3(64, 16), 256, 0, stream>>>(qkvb, ids, ctx);
        gemm64_f16<4><<<dim3(128, 4), 256, 0, stream>>>(
            ctx, WoT + (size_t)i * 65536, bo + i * 256, X, Y, nullptr, 256, 256);
        ln_kernel<<<2048, 256, 0, stream>>>(Y, lnw + i * 256, lnb + i * 256, Th);
        gemm_f16w<<<dim3(64, 8), 256, 0, stream>>>(
            Th, W1T + (size_t)i * 262144, b1 + i * 1024, Hb, 256, 1024);
        gemm64_f16<2><<<dim3(128, 4), 256, 0, stream>>>(
            Hb, W2T + (size_t)i * 262144, b2 + i * 256, nullptr, X, Xh, 1024, 256);
    }

    head1_kernel<<<8, 256, 0, stream>>>(X, ft1w, ft1b, h1W);
    head2_kernel<<<4, 256, 0, stream>>>(h1W, ft2w, ft2b, feW, out);
    head3_kernel<<<1, 64, 0, stream>>>(feW, clw, clb, out);
}